// Round 6
// baseline (192.909 us; speedup 1.0000x reference)
//
#include <hip/hip_runtime.h>
#include <hip/hip_bf16.h>
#include <cstdint>

static constexpr int BLK      = 256;
static constexpr int CAP      = 40;     // adj slots/node (80 B). P(deg>40)~3e-10.
static constexpr int BINSHIFT = 8;      // 256 nodes per bin
static constexpr int BINNODES = 1 << BINSHIFT;
static constexpr int BINCAP   = BINNODES * CAP / 2;  // 5120 pairs == adj seg bytes
static constexpr int EPB      = 1024;   // edges per binning block (4/thread)
static constexpr int OVMAX    = 1024;
static constexpr int NB2MAX   = 512;    // >= 2*nbins (392)

typedef __attribute__((ext_vector_type(8))) short bf16x8;
typedef __attribute__((ext_vector_type(4))) float f32x4;

__device__ __forceinline__ float bf16lo(uint32_t u) { return __uint_as_float(u << 16); }
__device__ __forceinline__ float bf16hi(uint32_t u) { return __uint_as_float(u & 0xffff0000u); }
__device__ __forceinline__ float bf16f(unsigned short u) { return __uint_as_float((uint32_t)u << 16); }
__device__ __forceinline__ unsigned short f2bf(float f) {
    __hip_bfloat16 h = __float2bfloat16(f);
    return *(unsigned short*)&h;
}

// ============================================================ BIN + CONV ===
// blocks [0, gbin):      counting-sort pass 1 (LDS-staged coalesced appends;
//   binof[] recorded at scatter time -> 3 independent LDS reads per item).
// blocks [gbin,+gxc):    x -> bf16 (xb), streaming.
// blocks [..,+8):        W -> bf16 transposed.
__global__ __launch_bounds__(BLK) void k_bin_conv(
        const int* __restrict__ src, const int* __restrict__ dst, int ne,
        uint32_t* __restrict__ pair, int* __restrict__ gcnt,
        int* __restrict__ ovcnt, int* __restrict__ ovlist, int nbins, int gbin,
        const float* __restrict__ x, uint32_t* __restrict__ xb32, int nxw, int gxc,
        const float* __restrict__ Wf, const float* __restrict__ Wb,
        unsigned short* __restrict__ WTf, unsigned short* __restrict__ WTb) {
    const int bid = blockIdx.x, tid = threadIdx.x;
    if (bid < gbin) {
        __shared__ uint32_t stage[EPB * 2];              // 8 KB
        __shared__ unsigned short binof[EPB * 2];        // 4 KB
        __shared__ int hist[NB2MAX];                     // histogram, then cursor
        __shared__ int lofs[NB2MAX];                     // local exclusive prefix
        __shared__ int gbase[NB2MAX];                    // reserved global base
        __shared__ int chunk[NB2MAX / 8];
        const int nb2 = 2 * nbins;
        for (int i = tid; i < nb2; i += BLK) hist[i] = 0;
        __syncthreads();

        int s[4], d[4];
        const int e0 = bid * EPB + tid;
#pragma unroll
        for (int k = 0; k < 4; ++k) {
            int e = e0 + k * BLK;
            bool v = e < ne;
            s[k] = v ? src[e] : -1;
            d[k] = v ? dst[e] : -1;
            if (v) {
                atomicAdd(&hist[d[k] >> BINSHIFT], 1);
                atomicAdd(&hist[nbins + (s[k] >> BINSHIFT)], 1);
            }
        }
        __syncthreads();

        const int nch = (nb2 + 7) >> 3;
        if (tid < nch) {
            int a = 0, base = tid << 3;
#pragma unroll
            for (int k = 0; k < 8; ++k) { int idx = base + k; if (idx < nb2) a += hist[idx]; }
            chunk[tid] = a;
        }
        __syncthreads();
        if (tid == 0) { int a = 0; for (int c = 0; c < nch; ++c) { int t = chunk[c]; chunk[c] = a; a += t; } }
        __syncthreads();
        for (int i = tid; i < nb2; i += BLK) {           // strided (r3 lesson)
            int a = chunk[i >> 3];
            for (int k = (i >> 3) << 3; k < i; ++k) a += hist[k];
            lofs[i] = a;
        }
        __syncthreads();
        for (int i = tid; i < nb2; i += BLK) {
            int c = hist[i];
            gbase[i] = c ? atomicAdd(&gcnt[i], c) : 0;
            hist[i] = lofs[i];
        }
        __syncthreads();
#pragma unroll
        for (int k = 0; k < 4; ++k) {
            if (s[k] >= 0) {
                int b0 = d[k] >> BINSHIFT;
                int p0 = atomicAdd(&hist[b0], 1);
                stage[p0] = ((uint32_t)d[k] << 16) | (uint32_t)s[k];
                binof[p0] = (unsigned short)b0;
                int b1 = nbins + (s[k] >> BINSHIFT);
                int p1 = atomicAdd(&hist[b1], 1);
                stage[p1] = ((uint32_t)s[k] << 16) | (uint32_t)d[k];
                binof[p1] = (unsigned short)b1;
            }
        }
        __syncthreads();
        int nval = ne - bid * EPB; if (nval > EPB) nval = EPB; if (nval < 0) nval = 0;
        const int total = 2 * nval;
        for (int i = tid; i < total; i += BLK) {
            int b = binof[i];
            int gidx = gbase[b] + (i - lofs[b]);
            if (gidx < BINCAP)
                pair[(size_t)b * BINCAP + gidx] = stage[i];
            else {
                int node = (int)(stage[i] >> 16);
                int q = atomicAdd(ovcnt, 1);
                if (q < OVMAX) ovlist[q] = (node << 1) | (b >= nbins ? 1 : 0);
            }
        }
        return;
    }
    if (bid < gbin + gxc) {
        int base = (bid - gbin) * 2048;
        int end = base + 2048; if (end > nxw) end = nxw;
        for (int i = base + tid; i < end; i += BLK) {
            float2 v = ((const float2*)x)[i];
            xb32[i] = ((uint32_t)f2bf(v.y) << 16) | (uint32_t)f2bf(v.x);
        }
        return;
    }
    int wb = bid - gbin - gxc;                           // 0..7
    for (int idx = wb * 2048 + tid; idx < (wb + 1) * 2048; idx += BLK) {
        int c = idx >> 7, k = idx & 127;
        WTf[c * 128 + k] = f2bf(Wf[k * 128 + c]);
        WTb[c * 128 + k] = f2bf(Wb[k * 128 + c]);
    }
}

// ============================================================ BUILD ========
// counting-sort pass 2: coalesced pair read -> LDS-atomic rank -> 20 KB LDS
// bucket image -> coalesced in-place dump. cnt + dinv computed here.
__global__ __launch_bounds__(BLK) void k_build(
        uint32_t* __restrict__ pair, const int* __restrict__ gcnt,
        int* __restrict__ cnt_f, int* __restrict__ cnt_b,
        float* __restrict__ dinv_f, float* __restrict__ dinv_b,
        int* __restrict__ ovcnt, int* __restrict__ ovlist,
        int n, int nbins) {
    const int bid = blockIdx.x, tid = threadIdx.x;
    __shared__ unsigned short buck[BINNODES * CAP];      // 20 KB
    __shared__ int lcnt[BINNODES];
    lcnt[tid] = 0;                                       // BLK == BINNODES
    __syncthreads();
    int count = gcnt[bid]; if (count > BINCAP) count = BINCAP;
    const uint32_t* pb = pair + (size_t)bid * BINCAP;
    const int dir = bid >= nbins ? 1 : 0;
    for (int i = tid; i < count; i += BLK) {
        uint32_t p = pb[i];
        int l = (p >> 16) & (BINNODES - 1);
        int r = atomicAdd(&lcnt[l], 1);
        if (r < CAP) buck[l * CAP + r] = (unsigned short)(p & 0xffffu);
        else {
            int q = atomicAdd(ovcnt, 1);
            if (q < OVMAX)
                ovlist[q] = (((((bid - dir * nbins) << BINSHIFT) + l)) << 1) | dir;
        }
    }
    __syncthreads();
    const int node = ((bid - dir * nbins) << BINSHIFT) + tid;
    if (node < n) {
        int c = lcnt[tid];
        if (dir) { cnt_b[node] = c; dinv_b[node] = rsqrtf(1.0f + (float)c); }
        else     { cnt_f[node] = c; dinv_f[node] = rsqrtf(1.0f + (float)c); }
    }
    uint32_t* seg = pair + (size_t)bid * BINCAP;
    const uint32_t* b32 = (const uint32_t*)buck;
    for (int i = tid; i < BINCAP; i += BLK) seg[i] = b32[i];
}

// ============================================================ GATHER/AGG ===
// r5 lesson: the gather phase is latency-bound — it wants max wave count
// (wave-per-node, 50000 waves), zero barriers, zero LDS. Un-fused from the
// GEMM (k_gemm_out does that in place over d_out).
// New: paired-neighbor uint2 loads — lane halves (h=lane>>5) own alternate
// neighbors; each lane loads 2 dwords (512 B/wave/instr, 2x r4). Final
// __shfl_xor(32) combines halves. Shfl + VMEM instr count per neighbor
// halves.
__device__ __forceinline__ void accum_pairs(
        int j0, int j1, int ofs, float sc,
        const uint32_t* __restrict__ xb, int c, int h,
        float& a00, float& a01, float& a10, float& a11) {
    int j = j0;
    for (; j + 8 <= j1; j += 8) {
        int   o0 = __shfl(ofs, j + 0 + h), o1 = __shfl(ofs, j + 2 + h);
        int   o2 = __shfl(ofs, j + 4 + h), o3 = __shfl(ofs, j + 6 + h);
        float s0 = __shfl(sc, j + 0 + h), s1 = __shfl(sc, j + 2 + h);
        float s2 = __shfl(sc, j + 4 + h), s3 = __shfl(sc, j + 6 + h);
        uint2 u0 = *(const uint2*)(xb + (size_t)o0 + 2 * c);
        uint2 u1 = *(const uint2*)(xb + (size_t)o1 + 2 * c);
        uint2 u2 = *(const uint2*)(xb + (size_t)o2 + 2 * c);
        uint2 u3 = *(const uint2*)(xb + (size_t)o3 + 2 * c);
        a00 = fmaf(s0, bf16lo(u0.x), a00); a01 = fmaf(s0, bf16hi(u0.x), a01);
        a10 = fmaf(s0, bf16lo(u0.y), a10); a11 = fmaf(s0, bf16hi(u0.y), a11);
        a00 = fmaf(s1, bf16lo(u1.x), a00); a01 = fmaf(s1, bf16hi(u1.x), a01);
        a10 = fmaf(s1, bf16lo(u1.y), a10); a11 = fmaf(s1, bf16hi(u1.y), a11);
        a00 = fmaf(s2, bf16lo(u2.x), a00); a01 = fmaf(s2, bf16hi(u2.x), a01);
        a10 = fmaf(s2, bf16lo(u2.y), a10); a11 = fmaf(s2, bf16hi(u2.y), a11);
        a00 = fmaf(s3, bf16lo(u3.x), a00); a01 = fmaf(s3, bf16hi(u3.x), a01);
        a10 = fmaf(s3, bf16lo(u3.y), a10); a11 = fmaf(s3, bf16hi(u3.y), a11);
    }
    for (; j + 2 <= j1; j += 2) {
        int   o0 = __shfl(ofs, j + h);
        float s0 = __shfl(sc, j + h);
        uint2 u0 = *(const uint2*)(xb + (size_t)o0 + 2 * c);
        a00 = fmaf(s0, bf16lo(u0.x), a00); a01 = fmaf(s0, bf16hi(u0.x), a01);
        a10 = fmaf(s0, bf16lo(u0.y), a10); a11 = fmaf(s0, bf16hi(u0.y), a11);
    }
    if (j < j1) {                         // odd tail: half 0 only
        int   o0 = __shfl(ofs, j);
        float s0 = __shfl(sc, j);
        if (h == 0) {
            uint2 u0 = *(const uint2*)(xb + (size_t)o0 + 2 * c);
            a00 = fmaf(s0, bf16lo(u0.x), a00); a01 = fmaf(s0, bf16hi(u0.x), a01);
            a10 = fmaf(s0, bf16lo(u0.y), a10); a11 = fmaf(s0, bf16hi(u0.y), a11);
        }
    }
}

__global__ __launch_bounds__(BLK) void k_gather_agg(
        const int* __restrict__ cnt_f, const int* __restrict__ cnt_b,
        const unsigned short* __restrict__ adj_f,
        const unsigned short* __restrict__ adj_b,
        const float* __restrict__ dinv_f, const float* __restrict__ dinv_b,
        const uint32_t* __restrict__ xb32,
        uint32_t* __restrict__ agg32,      // d_out; row = [f 64dw | b 64dw]
        int n, int gnode,
        const int* __restrict__ ovcnt, const int* __restrict__ ovlist,
        const int* __restrict__ src, const int* __restrict__ dst, int ne) {
    const int bid = blockIdx.x;
    if (bid < gnode) {
        const int wave = threadIdx.x >> 6;
        const int lane = threadIdx.x & 63;
        const int node = bid * 4 + wave;
        if (node >= n) return;

        int cf = cnt_f[node], cb = cnt_b[node];
        if (cf > CAP || cb > CAP) return;          // fixup owns this row

        const int c = lane & 31, h = lane >> 5;
        float dvsf = dinv_f[node], dvsb = dinv_b[node];
        float f00 = 0.f, f01 = 0.f, f10 = 0.f, f11 = 0.f;
        float b00 = 0.f, b01 = 0.f, b10 = 0.f, b11 = 0.f;
        {
            uint2 uv = *(const uint2*)(xb32 + (size_t)node * 64 + 2 * c);
            if (h == 0) {                          // self term once
                float wf = dvsf * dvsf, wb = dvsb * dvsb;
                f00 = wf * bf16lo(uv.x); f01 = wf * bf16hi(uv.x);
                f10 = wf * bf16lo(uv.y); f11 = wf * bf16hi(uv.y);
                b00 = wb * bf16lo(uv.x); b01 = wb * bf16hi(uv.x);
                b10 = wb * bf16lo(uv.y); b11 = wb * bf16hi(uv.y);
            }
        }

        const int mt = cf + cb;
        if (mt <= 64) {
            int ofs = 0; float sc = 0.f;
            if (lane < cf) {
                int nb = adj_f[node * CAP + lane];
                ofs = nb * 64;
                sc  = dvsf * dinv_f[nb];
            } else if (lane < mt) {
                int nb = adj_b[node * CAP + (lane - cf)];
                ofs = nb * 64;
                sc  = dvsb * dinv_b[nb];
            }
            accum_pairs(0,  cf, ofs, sc, xb32, c, h, f00, f01, f10, f11);
            accum_pairs(cf, mt, ofs, sc, xb32, c, h, b00, b01, b10, b11);
        } else {
            for (int j = h; j < cf; j += 2) {      // parity split over halves
                int nb = adj_f[node * CAP + j];
                float dj = dvsf * dinv_f[nb];
                uint2 u = *(const uint2*)(xb32 + (size_t)nb * 64 + 2 * c);
                f00 = fmaf(dj, bf16lo(u.x), f00); f01 = fmaf(dj, bf16hi(u.x), f01);
                f10 = fmaf(dj, bf16lo(u.y), f10); f11 = fmaf(dj, bf16hi(u.y), f11);
            }
            for (int j = h; j < cb; j += 2) {
                int nb = adj_b[node * CAP + j];
                float dj = dvsb * dinv_b[nb];
                uint2 u = *(const uint2*)(xb32 + (size_t)nb * 64 + 2 * c);
                b00 = fmaf(dj, bf16lo(u.x), b00); b01 = fmaf(dj, bf16hi(u.x), b01);
                b10 = fmaf(dj, bf16lo(u.y), b10); b11 = fmaf(dj, bf16hi(u.y), b11);
            }
        }
        // combine lane halves
        f00 += __shfl_xor(f00, 32); f01 += __shfl_xor(f01, 32);
        f10 += __shfl_xor(f10, 32); f11 += __shfl_xor(f11, 32);
        b00 += __shfl_xor(b00, 32); b01 += __shfl_xor(b01, 32);
        b10 += __shfl_xor(b10, 32); b11 += __shfl_xor(b11, 32);
        if (h == 0) {
            uint2 pf, pb2;
            pf.x  = ((uint32_t)f2bf(f01) << 16) | (uint32_t)f2bf(f00);
            pf.y  = ((uint32_t)f2bf(f11) << 16) | (uint32_t)f2bf(f10);
            pb2.x = ((uint32_t)f2bf(b01) << 16) | (uint32_t)f2bf(b00);
            pb2.y = ((uint32_t)f2bf(b11) << 16) | (uint32_t)f2bf(b10);
            *((uint2*)(agg32 + (size_t)node * 128) + c)      = pf;
            *((uint2*)(agg32 + (size_t)node * 128 + 64) + c) = pb2;
        }
        return;
    }

    // ---- fixup blocks: exact recompute of overflowed rows' agg (both dirs)
    int nov = *ovcnt; if (nov > OVMAX) nov = OVMAX;
    if (nov == 0) return;
    __shared__ int lst[2048];
    __shared__ int lc;
    const int tid = threadIdx.x;
    for (int i = bid - gnode; i < nov; i += 8) {
        int node = ovlist[i] >> 1;
        for (int d2 = 0; d2 < 2; ++d2) {
            const int* key = d2 ? src : dst;
            const int* val = d2 ? dst : src;
            const float* dinv = d2 ? dinv_b : dinv_f;
            float dvs = dinv[node];
            float s0 = 0.f, s1 = 0.f;
            if (tid < 64) {
                uint32_t u = xb32[(size_t)node * 64 + tid];
                s0 = dvs * bf16lo(u); s1 = dvs * bf16hi(u);
            }
            for (int start = 0; start < ne; start += 2048) {
                if (tid == 0) lc = 0;
                __syncthreads();
                int end = min(start + 2048, ne);
                for (int e2 = start + tid; e2 < end; e2 += BLK)
                    if (key[e2] == node) { int q = atomicAdd(&lc, 1); lst[q] = val[e2]; }
                __syncthreads();
                int mm = lc;
                if (tid < 64) {
                    for (int j = 0; j < mm; ++j) {
                        int nb = lst[j];
                        float dv = dinv[nb];
                        uint32_t u = xb32[(size_t)nb * 64 + tid];
                        s0 = fmaf(dv, bf16lo(u), s0);
                        s1 = fmaf(dv, bf16hi(u), s1);
                    }
                }
                __syncthreads();
            }
            if (tid < 64) {
                float a0 = dvs * s0, a1 = dvs * s1;
                agg32[(size_t)node * 128 + d2 * 64 + tid] =
                    ((uint32_t)f2bf(a1) << 16) | (uint32_t)f2bf(a0);
            }
            __syncthreads();
        }
    }
}

// ============================================================ GEMM OUT =====
// out = relu(aggf @ Wf + aggb @ Wb + bias), in place over the interleaved
// agg buffer (out row r's 512 B == agg row r's 512 B; each block touches
// only its own 32 rows; __syncthreads (vmcnt-draining) orders the in-place
// reads before any store). Validated in r4.
__global__ __launch_bounds__(BLK) void k_gemm_out(
        const unsigned short* __restrict__ agg,    // row stride 256: [f|b]
        const unsigned short* __restrict__ WTf,
        const unsigned short* __restrict__ WTb,
        const float* __restrict__ bfv, const float* __restrict__ bbv,
        float* __restrict__ out, int n) {
    const int wave = threadIdx.x >> 6, lane = threadIdx.x & 63;
    const int wm = wave >> 1, wh = wave & 1;
    const int q = lane >> 4, t16 = lane & 15;
    const int m0 = blockIdx.x * 32 + wm * 16;
    int arow = m0 + t16; if (arow >= n) arow = n - 1;
    const unsigned short* ra = agg + (size_t)arow * 256;
    bf16x8 af[4], ab[4];
#pragma unroll
    for (int s = 0; s < 4; ++s) {
        af[s] = *(const bf16x8*)(ra + s * 32 + q * 8);
        ab[s] = *(const bf16x8*)(ra + 128 + s * 32 + q * 8);
    }
    __syncthreads();     // all agg loads retired before in-place stores
#pragma unroll
    for (int t = 0; t < 4; ++t) {
        const int col = wh * 64 + t * 16 + t16;
        const unsigned short* wrf = WTf + (size_t)col * 128;
        const unsigned short* wrb = WTb + (size_t)col * 128;
        f32x4 c = {0.f, 0.f, 0.f, 0.f};
#pragma unroll
        for (int s = 0; s < 4; ++s)
            c = __builtin_amdgcn_mfma_f32_16x16x32_bf16(
                    af[s], *(const bf16x8*)(wrf + s * 32 + q * 8), c, 0, 0, 0);
#pragma unroll
        for (int s = 0; s < 4; ++s)
            c = __builtin_amdgcn_mfma_f32_16x16x32_bf16(
                    ab[s], *(const bf16x8*)(wrb + s * 32 + q * 8), c, 0, 0, 0);
        const float bias = bfv[col] + bbv[col];
#pragma unroll
        for (int r = 0; r < 4; ++r) {
            int row = m0 + q * 4 + r;
            if (row < n)
                out[(size_t)row * 128 + col] = fmaxf(c[r] + bias, 0.f);
        }
    }
}

// ============================================================ launcher =====
extern "C" void kernel_launch(void* const* d_in, const int* in_sizes, int n_in,
                              void* d_out, int out_size, void* d_ws, size_t ws_size,
                              hipStream_t stream) {
    const float* x  = (const float*)d_in[0];
    const int*   ei = (const int*)d_in[1];
    const float* Wf = (const float*)d_in[2];
    const float* bf = (const float*)d_in[3];
    const float* Wb = (const float*)d_in[4];
    const float* bb = (const float*)d_in[5];

    const int n  = in_sizes[0] / 128;   // 50000
    const int ne = in_sizes[1] / 2;     // 625000
    const int* src = ei;
    const int* dst = ei + ne;
    float* out = (float*)d_out;

    const int nbins = (n + BINNODES - 1) >> BINSHIFT;   // 196
    const int nb2   = 2 * nbins;                        // 392

    // workspace (pair/adj overlay; agg lives in d_out: n rows x 512 B)
    char* w = (char*)d_ws;
    uint32_t* pair = (uint32_t*)w;              w += (size_t)nb2 * BINCAP * 4;  // 8 MB
    uint32_t* xb32 = (uint32_t*)w;              w += (size_t)n * 64 * 4;        // 12.8 MB
    float* dinv_f = (float*)w;                  w += (size_t)n * 4;
    float* dinv_b = (float*)w;                  w += (size_t)n * 4;
    unsigned short* WTf = (unsigned short*)w;   w += 128 * 128 * 2;
    unsigned short* WTb = (unsigned short*)w;   w += 128 * 128 * 2;
    int* cnt_f = (int*)w;                       w += (size_t)n * 4;
    int* cnt_b = (int*)w;                       w += (size_t)n * 4;
    int* gcnt = (int*)w;                        w += (size_t)nb2 * 4;   // -- zero
    int* ovcnt = (int*)w;                       w += 8 * 4;             //  region
    int* ovlist = (int*)w;                      w += OVMAX * 4;

    const unsigned short* adj_f = (const unsigned short*)pair;
    const unsigned short* adj_b = adj_f + (size_t)nbins * BINNODES * CAP;
    uint32_t* agg32 = (uint32_t*)d_out;

    const int gbin  = (ne + EPB - 1) / EPB;             // 611
    const int gxc   = (n * 64 + 2047) / 2048;           // 1563
    const int gnode = (n + 3) / 4;                      // 12500
    const int ggo   = (n + 31) / 32;                    // 1563

    hipMemsetAsync(gcnt, 0, (size_t)(nb2 + 8) * 4, stream);

    k_bin_conv<<<gbin + gxc + 8, BLK, 0, stream>>>(src, dst, ne,
                                                   pair, gcnt, ovcnt, ovlist,
                                                   nbins, gbin,
                                                   x, xb32, n * 64, gxc,
                                                   Wf, Wb, WTf, WTb);

    k_build<<<nb2, BLK, 0, stream>>>(pair, gcnt, cnt_f, cnt_b,
                                     dinv_f, dinv_b, ovcnt, ovlist, n, nbins);

    k_gather_agg<<<gnode + 8, BLK, 0, stream>>>(cnt_f, cnt_b, adj_f, adj_b,
                                                dinv_f, dinv_b, xb32,
                                                agg32, n, gnode,
                                                ovcnt, ovlist, src, dst, ne);

    k_gemm_out<<<ggo, BLK, 0, stream>>>((const unsigned short*)agg32,
                                        WTf, WTb, bf, bb, out, n);
}

// Round 7
// 185.274 us; speedup vs baseline: 1.0412x; 1.0412x over previous
//
#include <hip/hip_runtime.h>
#include <hip/hip_bf16.h>
#include <cstdint>

static constexpr int BLK      = 256;
static constexpr int CAP      = 40;     // adj slots/node (80 B). P(deg>40)~3e-10.
static constexpr int BINSHIFT = 8;      // 256 nodes per bin
static constexpr int BINNODES = 1 << BINSHIFT;
static constexpr int BINCAP   = BINNODES * CAP / 2;  // 5120 pairs == adj seg bytes
static constexpr int EPB      = 1024;   // edges per binning block (4/thread)
static constexpr int OVMAX    = 1024;
static constexpr int NB2MAX   = 512;    // >= 2*nbins (392)

typedef __attribute__((ext_vector_type(8))) short bf16x8;
typedef __attribute__((ext_vector_type(4))) float f32x4;

__device__ __forceinline__ float bf16lo(uint32_t u) { return __uint_as_float(u << 16); }
__device__ __forceinline__ float bf16hi(uint32_t u) { return __uint_as_float(u & 0xffff0000u); }
__device__ __forceinline__ float bf16f(unsigned short u) { return __uint_as_float((uint32_t)u << 16); }
__device__ __forceinline__ unsigned short f2bf(float f) {
    __hip_bfloat16 h = __float2bfloat16(f);
    return *(unsigned short*)&h;
}

// ============================================================ BIN + CONV ===
// blocks [0, gbin):      counting-sort pass 1 (LDS-staged coalesced appends;
//   binof[] recorded at scatter time -> 3 independent LDS reads per item).
// blocks [gbin,+gxc):    x -> bf16 (xb), streaming.
// blocks [..,+8):        W -> bf16 transposed.
__global__ __launch_bounds__(BLK) void k_bin_conv(
        const int* __restrict__ src, const int* __restrict__ dst, int ne,
        uint32_t* __restrict__ pair, int* __restrict__ gcnt,
        int* __restrict__ ovcnt, int* __restrict__ ovlist, int nbins, int gbin,
        const float* __restrict__ x, uint32_t* __restrict__ xb32, int nxw, int gxc,
        const float* __restrict__ Wf, const float* __restrict__ Wb,
        unsigned short* __restrict__ WTf, unsigned short* __restrict__ WTb) {
    const int bid = blockIdx.x, tid = threadIdx.x;
    if (bid < gbin) {
        __shared__ uint32_t stage[EPB * 2];              // 8 KB
        __shared__ unsigned short binof[EPB * 2];        // 4 KB
        __shared__ int hist[NB2MAX];                     // histogram, then cursor
        __shared__ int lofs[NB2MAX];                     // local exclusive prefix
        __shared__ int gbase[NB2MAX];                    // reserved global base
        __shared__ int chunk[NB2MAX / 8];
        const int nb2 = 2 * nbins;
        for (int i = tid; i < nb2; i += BLK) hist[i] = 0;
        __syncthreads();

        int s[4], d[4];
        const int e0 = bid * EPB + tid;
#pragma unroll
        for (int k = 0; k < 4; ++k) {
            int e = e0 + k * BLK;
            bool v = e < ne;
            s[k] = v ? src[e] : -1;
            d[k] = v ? dst[e] : -1;
            if (v) {
                atomicAdd(&hist[d[k] >> BINSHIFT], 1);
                atomicAdd(&hist[nbins + (s[k] >> BINSHIFT)], 1);
            }
        }
        __syncthreads();

        const int nch = (nb2 + 7) >> 3;
        if (tid < nch) {
            int a = 0, base = tid << 3;
#pragma unroll
            for (int k = 0; k < 8; ++k) { int idx = base + k; if (idx < nb2) a += hist[idx]; }
            chunk[tid] = a;
        }
        __syncthreads();
        if (tid == 0) { int a = 0; for (int c = 0; c < nch; ++c) { int t = chunk[c]; chunk[c] = a; a += t; } }
        __syncthreads();
        for (int i = tid; i < nb2; i += BLK) {           // strided (r3 lesson)
            int a = chunk[i >> 3];
            for (int k = (i >> 3) << 3; k < i; ++k) a += hist[k];
            lofs[i] = a;
        }
        __syncthreads();
        for (int i = tid; i < nb2; i += BLK) {
            int c = hist[i];
            gbase[i] = c ? atomicAdd(&gcnt[i], c) : 0;
            hist[i] = lofs[i];
        }
        __syncthreads();
#pragma unroll
        for (int k = 0; k < 4; ++k) {
            if (s[k] >= 0) {
                int b0 = d[k] >> BINSHIFT;
                int p0 = atomicAdd(&hist[b0], 1);
                stage[p0] = ((uint32_t)d[k] << 16) | (uint32_t)s[k];
                binof[p0] = (unsigned short)b0;
                int b1 = nbins + (s[k] >> BINSHIFT);
                int p1 = atomicAdd(&hist[b1], 1);
                stage[p1] = ((uint32_t)s[k] << 16) | (uint32_t)d[k];
                binof[p1] = (unsigned short)b1;
            }
        }
        __syncthreads();
        int nval = ne - bid * EPB; if (nval > EPB) nval = EPB; if (nval < 0) nval = 0;
        const int total = 2 * nval;
        for (int i = tid; i < total; i += BLK) {
            int b = binof[i];
            int gidx = gbase[b] + (i - lofs[b]);
            if (gidx < BINCAP)
                pair[(size_t)b * BINCAP + gidx] = stage[i];
            else {
                int node = (int)(stage[i] >> 16);
                int q = atomicAdd(ovcnt, 1);
                if (q < OVMAX) ovlist[q] = (node << 1) | (b >= nbins ? 1 : 0);
            }
        }
        return;
    }
    if (bid < gbin + gxc) {
        int base = (bid - gbin) * 2048;
        int end = base + 2048; if (end > nxw) end = nxw;
        for (int i = base + tid; i < end; i += BLK) {
            float2 v = ((const float2*)x)[i];
            xb32[i] = ((uint32_t)f2bf(v.y) << 16) | (uint32_t)f2bf(v.x);
        }
        return;
    }
    int wb = bid - gbin - gxc;                           // 0..7
    for (int idx = wb * 2048 + tid; idx < (wb + 1) * 2048; idx += BLK) {
        int c = idx >> 7, k = idx & 127;
        WTf[c * 128 + k] = f2bf(Wf[k * 128 + c]);
        WTb[c * 128 + k] = f2bf(Wb[k * 128 + c]);
    }
}

// ============================================================ BUILD ========
// counting-sort pass 2: coalesced pair read -> LDS-atomic rank -> 20 KB LDS
// bucket image -> coalesced in-place dump. cnt + dinv computed here.
__global__ __launch_bounds__(BLK) void k_build(
        uint32_t* __restrict__ pair, const int* __restrict__ gcnt,
        int* __restrict__ cnt_f, int* __restrict__ cnt_b,
        float* __restrict__ dinv_f, float* __restrict__ dinv_b,
        int* __restrict__ ovcnt, int* __restrict__ ovlist,
        int n, int nbins) {
    const int bid = blockIdx.x, tid = threadIdx.x;
    __shared__ unsigned short buck[BINNODES * CAP];      // 20 KB
    __shared__ int lcnt[BINNODES];
    lcnt[tid] = 0;                                       // BLK == BINNODES
    __syncthreads();
    int count = gcnt[bid]; if (count > BINCAP) count = BINCAP;
    const uint32_t* pb = pair + (size_t)bid * BINCAP;
    const int dir = bid >= nbins ? 1 : 0;
    for (int i = tid; i < count; i += BLK) {
        uint32_t p = pb[i];
        int l = (p >> 16) & (BINNODES - 1);
        int r = atomicAdd(&lcnt[l], 1);
        if (r < CAP) buck[l * CAP + r] = (unsigned short)(p & 0xffffu);
        else {
            int q = atomicAdd(ovcnt, 1);
            if (q < OVMAX)
                ovlist[q] = (((((bid - dir * nbins) << BINSHIFT) + l)) << 1) | dir;
        }
    }
    __syncthreads();
    const int node = ((bid - dir * nbins) << BINSHIFT) + tid;
    if (node < n) {
        int c = lcnt[tid];
        if (dir) { cnt_b[node] = c; dinv_b[node] = rsqrtf(1.0f + (float)c); }
        else     { cnt_f[node] = c; dinv_f[node] = rsqrtf(1.0f + (float)c); }
    }
    uint32_t* seg = pair + (size_t)bid * BINCAP;
    const uint32_t* b32 = (const uint32_t*)buck;
    for (int i = tid; i < BINCAP; i += BLK) seg[i] = b32[i];
}

// ============================================================ GATHER+GEMM ==
// r6 lesson: gather is BYTE-bound (~3.3 TB/s L2-miss path; uint2 pairing was
// a null) -> keep r4's plain inner loop. r5+r6 lesson: fusion is right
// (saves a dispatch ~10-15us + 50 MB agg round-trip) but must keep
// wave-per-node TLP: 1024-thread blocks, 16 waves, wave owns one node.
// Agg tile 16x256 bf16 in LDS (528 B pitch -> 2-way = free); MFMA epilogue
// on waves 0-7 (one 16-col tile each). No early return before the barrier
// (skip via predication). launch_bounds(1024,8) pins VGPR<=64 -> 2 blk/CU
// = 32 waves/CU for the gather phase.
__device__ __forceinline__ void accum_range(
        int j0, int j1, int ofs, float sc,
        const uint32_t* __restrict__ xb, int lane, float& a0, float& a1) {
    int j = j0;
    for (; j + 8 <= j1; j += 8) {
        int   o0 = __shfl(ofs, j + 0), o1 = __shfl(ofs, j + 1);
        int   o2 = __shfl(ofs, j + 2), o3 = __shfl(ofs, j + 3);
        int   o4 = __shfl(ofs, j + 4), o5 = __shfl(ofs, j + 5);
        int   o6 = __shfl(ofs, j + 6), o7 = __shfl(ofs, j + 7);
        float s0 = __shfl(sc, j + 0), s1 = __shfl(sc, j + 1);
        float s2 = __shfl(sc, j + 2), s3 = __shfl(sc, j + 3);
        float s4 = __shfl(sc, j + 4), s5 = __shfl(sc, j + 5);
        float s6 = __shfl(sc, j + 6), s7 = __shfl(sc, j + 7);
        uint32_t u0 = xb[(size_t)(o0 + lane)], u1 = xb[(size_t)(o1 + lane)];
        uint32_t u2 = xb[(size_t)(o2 + lane)], u3 = xb[(size_t)(o3 + lane)];
        uint32_t u4 = xb[(size_t)(o4 + lane)], u5 = xb[(size_t)(o5 + lane)];
        uint32_t u6 = xb[(size_t)(o6 + lane)], u7 = xb[(size_t)(o7 + lane)];
        a0 = fmaf(s0, bf16lo(u0), a0); a1 = fmaf(s0, bf16hi(u0), a1);
        a0 = fmaf(s1, bf16lo(u1), a0); a1 = fmaf(s1, bf16hi(u1), a1);
        a0 = fmaf(s2, bf16lo(u2), a0); a1 = fmaf(s2, bf16hi(u2), a1);
        a0 = fmaf(s3, bf16lo(u3), a0); a1 = fmaf(s3, bf16hi(u3), a1);
        a0 = fmaf(s4, bf16lo(u4), a0); a1 = fmaf(s4, bf16hi(u4), a1);
        a0 = fmaf(s5, bf16lo(u5), a0); a1 = fmaf(s5, bf16hi(u5), a1);
        a0 = fmaf(s6, bf16lo(u6), a0); a1 = fmaf(s6, bf16hi(u6), a1);
        a0 = fmaf(s7, bf16lo(u7), a0); a1 = fmaf(s7, bf16hi(u7), a1);
    }
    for (; j + 4 <= j1; j += 4) {
        int   o0 = __shfl(ofs, j + 0), o1 = __shfl(ofs, j + 1);
        int   o2 = __shfl(ofs, j + 2), o3 = __shfl(ofs, j + 3);
        float s0 = __shfl(sc, j + 0), s1 = __shfl(sc, j + 1);
        float s2 = __shfl(sc, j + 2), s3 = __shfl(sc, j + 3);
        uint32_t u0 = xb[(size_t)(o0 + lane)], u1 = xb[(size_t)(o1 + lane)];
        uint32_t u2 = xb[(size_t)(o2 + lane)], u3 = xb[(size_t)(o3 + lane)];
        a0 = fmaf(s0, bf16lo(u0), a0); a1 = fmaf(s0, bf16hi(u0), a1);
        a0 = fmaf(s1, bf16lo(u1), a0); a1 = fmaf(s1, bf16hi(u1), a1);
        a0 = fmaf(s2, bf16lo(u2), a0); a1 = fmaf(s2, bf16hi(u2), a1);
        a0 = fmaf(s3, bf16lo(u3), a0); a1 = fmaf(s3, bf16hi(u3), a1);
    }
    for (; j < j1; ++j) {
        int oj = __shfl(ofs, j); float sj = __shfl(sc, j);
        uint32_t uj = xb[(size_t)(oj + lane)];
        a0 = fmaf(sj, bf16lo(uj), a0); a1 = fmaf(sj, bf16hi(uj), a1);
    }
}

__global__ __launch_bounds__(1024, 8) void k_gather_gemm(
        const int* __restrict__ cnt_f, const int* __restrict__ cnt_b,
        const unsigned short* __restrict__ adj_f,
        const unsigned short* __restrict__ adj_b,
        const float* __restrict__ dinv_f, const float* __restrict__ dinv_b,
        const uint32_t* __restrict__ xb32,
        const unsigned short* __restrict__ WTf,
        const unsigned short* __restrict__ WTb,
        const float* __restrict__ bfv, const float* __restrict__ bbv,
        float* __restrict__ out, int n, int gnode2,
        const int* __restrict__ ovcnt, const int* __restrict__ ovlist,
        const int* __restrict__ src, const int* __restrict__ dst, int ne) {
    __shared__ uint32_t aggL[16 * 132];   // 16 rows x 528 B pitch
    __shared__ int ovflag[16];
    __shared__ int lst[2048];             // fixup scratch
    __shared__ int lc;
    const int bid = blockIdx.x, tid = threadIdx.x;
    if (bid < gnode2) {
        const int wave = tid >> 6, lane = tid & 63;
        const int node = bid * 16 + wave;

        int cf = 0, cb = 0;
        bool skip = node >= n;
        if (!skip) { cf = cnt_f[node]; cb = cnt_b[node]; skip = (cf > CAP || cb > CAP); }
        if (lane == 0) ovflag[wave] = skip ? 1 : 0;

        if (!skip) {
            float dvsf = dinv_f[node], dvsb = dinv_b[node];
            uint32_t uv = xb32[(size_t)node * 64 + lane];
            float accf0 = dvsf * dvsf * bf16lo(uv), accf1 = dvsf * dvsf * bf16hi(uv);
            float accb0 = dvsb * dvsb * bf16lo(uv), accb1 = dvsb * dvsb * bf16hi(uv);

            const int mt = cf + cb;
            if (mt <= 64) {
                int ofs = 0; float sc = 0.f;
                if (lane < cf) {
                    int nb = adj_f[node * CAP + lane];
                    ofs = nb * 64;
                    sc  = dvsf * dinv_f[nb];
                } else if (lane < mt) {
                    int nb = adj_b[node * CAP + (lane - cf)];
                    ofs = nb * 64;
                    sc  = dvsb * dinv_b[nb];
                }
                accum_range(0,  cf, ofs, sc, xb32, lane, accf0, accf1);
                accum_range(cf, mt, ofs, sc, xb32, lane, accb0, accb1);
            } else {
                for (int j = 0; j < cf; ++j) {
                    int nb = adj_f[node * CAP + j];
                    float dj = dvsf * dinv_f[nb];
                    uint32_t u = xb32[(size_t)nb * 64 + lane];
                    accf0 = fmaf(dj, bf16lo(u), accf0); accf1 = fmaf(dj, bf16hi(u), accf1);
                }
                for (int j = 0; j < cb; ++j) {
                    int nb = adj_b[node * CAP + j];
                    float dj = dvsb * dinv_b[nb];
                    uint32_t u = xb32[(size_t)nb * 64 + lane];
                    accb0 = fmaf(dj, bf16lo(u), accb0); accb1 = fmaf(dj, bf16hi(u), accb1);
                }
            }
            aggL[wave * 132 + lane] =
                ((uint32_t)f2bf(accf1) << 16) | (uint32_t)f2bf(accf0);
            aggL[wave * 132 + 64 + lane] =
                ((uint32_t)f2bf(accb1) << 16) | (uint32_t)f2bf(accb0);
        }
        __syncthreads();

        // ---- fused MFMA epilogue: waves 0-7, one 16-col tile each ----
        if (wave < 8) {
            const int q = lane >> 4, t16 = lane & 15;
            const int col = wave * 16 + t16;
            const char* arow = (const char*)aggL + t16 * 528;
            const unsigned short* wrf = WTf + (size_t)col * 128;
            const unsigned short* wrb = WTb + (size_t)col * 128;
            f32x4 c = {0.f, 0.f, 0.f, 0.f};
#pragma unroll
            for (int s = 0; s < 4; ++s)
                c = __builtin_amdgcn_mfma_f32_16x16x32_bf16(
                        *(const bf16x8*)(arow + s * 64 + q * 16),
                        *(const bf16x8*)(wrf + s * 32 + q * 8), c, 0, 0, 0);
#pragma unroll
            for (int s = 0; s < 4; ++s)
                c = __builtin_amdgcn_mfma_f32_16x16x32_bf16(
                        *(const bf16x8*)(arow + 256 + s * 64 + q * 16),
                        *(const bf16x8*)(wrb + s * 32 + q * 8), c, 0, 0, 0);
            const float bias = bfv[col] + bbv[col];
#pragma unroll
            for (int r = 0; r < 4; ++r) {
                int row = q * 4 + r;
                int node2 = bid * 16 + row;
                if (node2 < n && !ovflag[row])
                    out[(size_t)node2 * 128 + col] = fmaxf(c[r] + bias, 0.f);
            }
        }
        return;
    }

    // ---- fixup blocks: exact recompute of overflowed rows (agg + GEMV) ----
    int nov = *ovcnt; if (nov > OVMAX) nov = OVMAX;
    if (nov == 0) return;
    float* aggfl = (float*)aggL;                          // [256] f then b
    for (int i = bid - gnode2; i < nov; i += 8) {
        int node = ovlist[i] >> 1;
        for (int d2 = 0; d2 < 2; ++d2) {
            const int* key = d2 ? src : dst;
            const int* val = d2 ? dst : src;
            const float* dinv = d2 ? dinv_b : dinv_f;
            float dvs = dinv[node];
            float s0 = 0.f, s1 = 0.f;
            if (tid < 64) {
                uint32_t u = xb32[(size_t)node * 64 + tid];
                s0 = dvs * bf16lo(u); s1 = dvs * bf16hi(u);
            }
            for (int start = 0; start < ne; start += 2048) {
                if (tid == 0) lc = 0;
                __syncthreads();
                int end = min(start + 2048, ne);
                for (int e2 = start + tid; e2 < end; e2 += 1024)
                    if (key[e2] == node) { int qq = atomicAdd(&lc, 1); lst[qq] = val[e2]; }
                __syncthreads();
                int mm = lc;
                if (tid < 64) {
                    for (int j = 0; j < mm; ++j) {
                        int nb = lst[j];
                        float dv = dinv[nb];
                        uint32_t u = xb32[(size_t)nb * 64 + tid];
                        s0 = fmaf(dv, bf16lo(u), s0);
                        s1 = fmaf(dv, bf16hi(u), s1);
                    }
                }
                __syncthreads();
            }
            if (tid < 64) {                 // bf16-round to match main path
                aggfl[d2 * 128 + 2 * tid]     = bf16f(f2bf(dvs * s0));
                aggfl[d2 * 128 + 2 * tid + 1] = bf16f(f2bf(dvs * s1));
            }
            __syncthreads();
        }
        if (tid < 128) {
            const int col = tid;
            float acc = bfv[col] + bbv[col];
            const unsigned short* wrf = WTf + (size_t)col * 128;
            const unsigned short* wrb = WTb + (size_t)col * 128;
            for (int k = 0; k < 128; ++k) {
                acc = fmaf(aggfl[k],       bf16f(wrf[k]), acc);
                acc = fmaf(aggfl[128 + k], bf16f(wrb[k]), acc);
            }
            out[(size_t)node * 128 + col] = fmaxf(acc, 0.f);
        }
        __syncthreads();
    }
}

// ============================================================ launcher =====
extern "C" void kernel_launch(void* const* d_in, const int* in_sizes, int n_in,
                              void* d_out, int out_size, void* d_ws, size_t ws_size,
                              hipStream_t stream) {
    const float* x  = (const float*)d_in[0];
    const int*   ei = (const int*)d_in[1];
    const float* Wf = (const float*)d_in[2];
    const float* bf = (const float*)d_in[3];
    const float* Wb = (const float*)d_in[4];
    const float* bb = (const float*)d_in[5];

    const int n  = in_sizes[0] / 128;   // 50000
    const int ne = in_sizes[1] / 2;     // 625000
    const int* src = ei;
    const int* dst = ei + ne;
    float* out = (float*)d_out;

    const int nbins = (n + BINNODES - 1) >> BINSHIFT;   // 196
    const int nb2   = 2 * nbins;                        // 392

    // workspace (pair/adj overlay; agg lives only in LDS)
    char* w = (char*)d_ws;
    uint32_t* pair = (uint32_t*)w;              w += (size_t)nb2 * BINCAP * 4;  // 8 MB
    uint32_t* xb32 = (uint32_t*)w;              w += (size_t)n * 64 * 4;        // 12.8 MB
    float* dinv_f = (float*)w;                  w += (size_t)n * 4;
    float* dinv_b = (float*)w;                  w += (size_t)n * 4;
    unsigned short* WTf = (unsigned short*)w;   w += 128 * 128 * 2;
    unsigned short* WTb = (unsigned short*)w;   w += 128 * 128 * 2;
    int* cnt_f = (int*)w;                       w += (size_t)n * 4;
    int* cnt_b = (int*)w;                       w += (size_t)n * 4;
    int* gcnt = (int*)w;                        w += (size_t)nb2 * 4;   // -- zero
    int* ovcnt = (int*)w;                       w += 8 * 4;             //  region
    int* ovlist = (int*)w;                      w += OVMAX * 4;

    const unsigned short* adj_f = (const unsigned short*)pair;
    const unsigned short* adj_b = adj_f + (size_t)nbins * BINNODES * CAP;

    const int gbin   = (ne + EPB - 1) / EPB;            // 611
    const int gxc    = (n * 64 + 2047) / 2048;          // 1563
    const int gnode2 = (n + 15) / 16;                   // 3125

    hipMemsetAsync(gcnt, 0, (size_t)(nb2 + 8) * 4, stream);

    k_bin_conv<<<gbin + gxc + 8, BLK, 0, stream>>>(src, dst, ne,
                                                   pair, gcnt, ovcnt, ovlist,
                                                   nbins, gbin,
                                                   x, xb32, n * 64, gxc,
                                                   Wf, Wb, WTf, WTb);

    k_build<<<nb2, BLK, 0, stream>>>(pair, gcnt, cnt_f, cnt_b,
                                     dinv_f, dinv_b, ovcnt, ovlist, n, nbins);

    k_gather_gemm<<<gnode2 + 8, 1024, 0, stream>>>(cnt_f, cnt_b, adj_f, adj_b,
                                                   dinv_f, dinv_b, xb32,
                                                   WTf, WTb, bf, bb,
                                                   out, n, gnode2,
                                                   ovcnt, ovlist, src, dst, ne);
}